// Round 6
// baseline (195.096 us; speedup 1.0000x reference)
//
#include <hip/hip_runtime.h>
#include <math.h>
#include <float.h>

#define W 1024
#define IMG_SZ (1024*1024)
#define RPC 16                        // interior rows per chunk
#define CPI 64                        // chunks per image
#define TOTAL_CHUNKS (32*CPI)         // 2048
#define NBLK 1024                     // 2 chunks per block (tid bit 7 selects)

// curv = Dxy*(Dx-Dy)^2 / (2h*(Dx^2+Dy^2)^1.5 + 16 h^4 * 1e-8)
#define TWO_H    0.122f
#define C_EPS    2.2153332e-12f       // 16 * 0.061^4 * 1e-8

struct Px { float num, den, mn; };

// Pixel x = x8+j; window w[0..9] covers x8-1 .. x8+8.
__device__ __forceinline__ Px px(const float T[10], const float M[10],
                                 const float B[10], int j) {
    Px p;
    const float Dx  = M[j+2] - M[j];
    const float Dy  = B[j+1] - T[j+1];
    const float Dxy = (B[j+2] - B[j]) - T[j+2] + T[j];
    const float dif = Dx - Dy;
    p.num = Dxy * (dif * dif);
    const float s = Dx*Dx + Dy*Dy;
    p.den = TWO_H * (s * __builtin_amdgcn_sqrtf(s)) + C_EPS;
    const float c = M[j+1];
    p.mn = fminf(fminf(c*M[j], c*M[j+2]), fminf(c*T[j+1], c*B[j+1]));
    return p;
}

// Shared reciprocal: den>=C_EPS so den_a*den_b >= 4.9e-24 (normal, no underflow).
__device__ __forceinline__ void pair(const Px& a, const Px& b, float ea, float eb,
                                     float& fsum, int& cnt) {
    const float rc = __builtin_amdgcn_rcpf(a.den * b.den);
    const float t0 = a.num * (b.den * rc);
    const float t1 = b.num * (a.den * rc);
    const float cr0 = fmaxf(t0*t0 - 1.0f, 0.0f);
    const float cr1 = fmaxf(t1*t1 - 1.0f, 0.0f);
    const bool k0 = fmaxf(a.mn, ea) < 0.0f;
    const bool k1 = fmaxf(b.mn, eb) < 0.0f;
    fsum += k0 ? cr0 : 0.0f;
    fsum += k1 ? cr1 : 0.0f;
    cnt += __popcll(__ballot(k0));    // scalar-pipe; cnt becomes wave-uniform
    cnt += __popcll(__ballot(k1));
}

__device__ __forceinline__ void do_row(const float T[10], const float M[10],
                                       const float B[10], float e0, float e7,
                                       float& fsum, int& cnt) {
    { Px a = px(T,M,B,0), b = px(T,M,B,1); pair(a, b, e0,       -FLT_MAX, fsum, cnt); }
    { Px a = px(T,M,B,2), b = px(T,M,B,3); pair(a, b, -FLT_MAX, -FLT_MAX, fsum, cnt); }
    { Px a = px(T,M,B,4), b = px(T,M,B,5); pair(a, b, -FLT_MAX, -FLT_MAX, fsum, cnt); }
    { Px a = px(T,M,B,6), b = px(T,M,B,7); pair(a, b, -FLT_MAX, e7,       fsum, cnt); }
}

// 8 px from one base: two float4 (imm offsets 0,16) + 2 halo scalars.
__device__ __forceinline__ void load_win(const float* __restrict__ p,
                                         int offL, int offR, float w[10]) {
    const float4 v0 = *reinterpret_cast<const float4*>(p);
    const float4 v1 = *reinterpret_cast<const float4*>(p + 4);
    w[1]=v0.x; w[2]=v0.y; w[3]=v0.z; w[4]=v0.w;
    w[5]=v1.x; w[6]=v1.y; w[7]=v1.z; w[8]=v1.w;
    w[0]=p[offL]; w[9]=p[offR];
}

__global__ __launch_bounds__(256) void curv_partial(const float* __restrict__ phi,
                                                    double* __restrict__ partial,
                                                    int nb) {
    const int xt   = threadIdx.x & 127;      // 0..127: 8-px strip, x = 8*xt..8*xt+7
    const int half = threadIdx.x >> 7;       // which of the block's 2 chunks
    const int x8   = xt * 8;
    const int offL = (xt > 0)   ? -1 : 0;    // clamped halo (edge-masked below)
    const int offR = (xt < 127) ? 8 : 7;
    const float e0 = (xt == 0)   ? 1.0f : -FLT_MAX;   // kills x=0
    const float e7 = (xt == 127) ? 1.0f : -FLT_MAX;   // kills x=1023

    double sum = 0.0, dcnt = 0.0;

    for (int chunk = (int)blockIdx.x * 2 + half; chunk < TOTAL_CHUNKS; chunk += nb * 2) {
        const int n  = chunk >> 6;
        const int ci = chunk & 63;
        const int y0 = 1 + ci * RPC;
        const float* p = phi + (size_t)n * IMG_SZ + (size_t)(y0 - 1) * W + x8;

        float fsum = 0.0f;
        int cnt = 0;
        float A[10], Bw[10], Cw[10];
        load_win(p, offL, offR, A);  p += W;   // row y0-1
        load_win(p, offL, offR, Bw); p += W;   // row y0

        if (ci != CPI - 1) {
            // hot path: full 16 interior rows, branch-free ring, fully unrolled
#pragma unroll
            for (int rr = 0; rr < 15; rr += 3) {
                load_win(p, offL, offR, Cw); p += W;
                do_row(A, Bw, Cw, e0, e7, fsum, cnt);
                load_win(p, offL, offR, A);  p += W;
                do_row(Bw, Cw, A, e0, e7, fsum, cnt);
                load_win(p, offL, offR, Bw); p += W;
                do_row(Cw, A, Bw, e0, e7, fsum, cnt);
            }
            load_win(p, offL, offR, Cw);
            do_row(A, Bw, Cw, e0, e7, fsum, cnt);       // 16th row
        } else {
            // tail chunk (y0=1009): 14 interior rows, rolled
            const int nri = 1023 - y0;
            for (int r = 0; r < nri; ++r) {
                load_win(p, offL, offR, Cw); p += W;
                do_row(A, Bw, Cw, e0, e7, fsum, cnt);
#pragma unroll
                for (int k = 0; k < 10; ++k) { A[k] = Bw[k]; Bw[k] = Cw[k]; }
            }
        }
        sum  += (double)fsum;
        dcnt += (double)cnt;                  // wave-uniform
    }

    // fsum: shuffle-reduce across wave; cnt already wave-uniform
    for (int off = 32; off > 0; off >>= 1)
        sum += __shfl_down(sum, off, 64);
    __shared__ double lsum[4], lcnt[4];
    const int lane = threadIdx.x & 63, wv = threadIdx.x >> 6;
    if (lane == 0) { lsum[wv] = sum; lcnt[wv] = dcnt; }
    __syncthreads();
    if (threadIdx.x == 0) {
        partial[blockIdx.x]      = lsum[0] + lsum[1] + lsum[2] + lsum[3];
        partial[nb + blockIdx.x] = lcnt[0] + lcnt[1] + lcnt[2] + lcnt[3];
    }
}

__global__ __launch_bounds__(256) void curv_final(const double* __restrict__ partial,
                                                  int nb, float* __restrict__ out) {
    double s = 0.0, c = 0.0;
    for (int i = threadIdx.x; i < nb; i += 256) {
        s += partial[i];
        c += partial[nb + i];
    }
    for (int off = 32; off > 0; off >>= 1) {
        s += __shfl_down(s, off, 64);
        c += __shfl_down(c, off, 64);
    }
    __shared__ double lsum[4], lcnt[4];
    const int lane = threadIdx.x & 63, wv = threadIdx.x >> 6;
    if (lane == 0) { lsum[wv] = s; lcnt[wv] = c; }
    __syncthreads();
    if (threadIdx.x == 0) {
        const double S = lsum[0] + lsum[1] + lsum[2] + lsum[3];
        const double C = lcnt[0] + lcnt[1] + lcnt[2] + lcnt[3];
        out[0] = (float)(S / (C + 1e-8));
    }
}

extern "C" void kernel_launch(void* const* d_in, const int* in_sizes, int n_in,
                              void* d_out, int out_size, void* d_ws, size_t ws_size,
                              hipStream_t stream) {
    const float* phi = (const float*)d_in[0];
    float* out = (float*)d_out;
    double* partial = (double*)d_ws;

    int nb = NBLK;
    const size_t need = (size_t)nb * 2 * sizeof(double);
    if (ws_size < need) {
        nb = (int)(ws_size / (2 * sizeof(double)));
        if (nb < 1) nb = 1;
    }

    curv_partial<<<nb, 256, 0, stream>>>(phi, partial, nb);
    curv_final<<<1, 256, 0, stream>>>(partial, nb, out);
}